// Round 6
// baseline (174.865 us; speedup 1.0000x reference)
//
#include <hip/hip_runtime.h>

#define EMBED 1024
#define HEAD 64
#define SEQ 4096

typedef __attribute__((ext_vector_type(8))) short short8;
typedef __attribute__((ext_vector_type(4))) float f32x4;

union S8u { short8 v; uint u[4]; ushort s[8]; };

__device__ __forceinline__ ushort f2bf(float f) {
  union { float f; uint u; } x; x.f = f;
  return (ushort)((x.u + 0x7fffu + ((x.u >> 16) & 1u)) >> 16);
}

__device__ __forceinline__ short8 ld16(const ushort* p) {
  uint4 q = *(const uint4*)p;
  S8u t; t.u[0] = q.x; t.u[1] = q.y; t.u[2] = q.z; t.u[3] = q.w;
  return t.v;
}

// ---------------- kernel 1: transpose weights to bf16 wT[t][c][k] ----------------
__global__ __launch_bounds__(256) void prep_w(const float* __restrict__ wq,
                                              const float* __restrict__ wk,
                                              const float* __restrict__ wv,
                                              ushort* __restrict__ wT) {
  int idx = blockIdx.x * 256 + threadIdx.x;
  if (idx >= 3 * HEAD * EMBED) return;
  int t = idx >> 16;
  int rem = idx & 0xFFFF;
  int c = rem >> 10;
  int k = rem & 1023;
  const float* w = (t == 0) ? wq : (t == 1) ? wk : wv;
  wT[idx] = f2bf(w[k * HEAD + c]);
}

// ------ kernel 2: projections -> q_bf16 (scale 0.125*log2e), k_bf16, v^T bf16 -----
__global__ __launch_bounds__(256) void proj_kernel(
    const float* __restrict__ qsrc, const float* __restrict__ ksrc,
    const float* __restrict__ vsrc, const ushort* __restrict__ wT,
    ushort* __restrict__ qb, ushort* __restrict__ kb, ushort* __restrict__ vt) {
  __shared__ ushort vtile[64][72];
  int t = blockIdx.y;
  const float* src = (t == 0) ? qsrc : (t == 1) ? ksrc : vsrc;
  const ushort* wt = wT + t * (HEAD * EMBED);
  int lane = threadIdx.x & 63;
  int wid = threadIdx.x >> 6;
  int c = lane & 15;
  int g = lane >> 4;
  int arow_i = blockIdx.x * 64 + wid * 16 + c;
  const float* arow = src + (size_t)arow_i * EMBED;

  f32x4 acc[4];
#pragma unroll
  for (int i = 0; i < 4; ++i) acc[i] = {0.f, 0.f, 0.f, 0.f};

#pragma unroll 8
  for (int k0 = 0; k0 < EMBED; k0 += 32) {
    float4 a0 = *(const float4*)(arow + k0 + 8 * g);
    float4 a1 = *(const float4*)(arow + k0 + 8 * g + 4);
    S8u a;
    a.s[0] = f2bf(a0.x); a.s[1] = f2bf(a0.y); a.s[2] = f2bf(a0.z); a.s[3] = f2bf(a0.w);
    a.s[4] = f2bf(a1.x); a.s[5] = f2bf(a1.y); a.s[6] = f2bf(a1.z); a.s[7] = f2bf(a1.w);
#pragma unroll
    for (int nf = 0; nf < 4; ++nf) {
      short8 b = ld16(wt + (size_t)(nf * 16 + c) * EMBED + k0 + 8 * g);
      acc[nf] = __builtin_amdgcn_mfma_f32_16x16x32_bf16(a.v, b, acc[nf], 0, 0, 0);
    }
  }

  if (t == 2) {
#pragma unroll
    for (int nf = 0; nf < 4; ++nf)
#pragma unroll
      for (int r = 0; r < 4; ++r)
        vtile[nf * 16 + c][wid * 16 + 4 * g + r] = f2bf(acc[nf][r]);
    __syncthreads();
    int d = threadIdx.x >> 2;
    int s0 = (threadIdx.x & 3) << 4;
    int row0 = blockIdx.x * 64;
    int bb = row0 >> 12;
    int sbase = row0 & (SEQ - 1);
    ushort* dst = vt + ((size_t)(bb * HEAD + d) << 12) + sbase + s0;
    const uint4* srcp = (const uint4*)&vtile[d][s0];
    *(uint4*)dst = srcp[0];
    *(uint4*)(dst + 8) = srcp[1];
  } else {
    int row_base = blockIdx.x * 64 + wid * 16 + 4 * g;
    float scale = (t == 0) ? 0.18033688011112042f : 1.0f;  // 0.125*log2(e)
    ushort* dstb = (t == 0) ? qb : kb;
#pragma unroll
    for (int nf = 0; nf < 4; ++nf)
#pragma unroll
      for (int r = 0; r < 4; ++r)
        dstb[(size_t)(row_base + r) * HEAD + nf * 16 + c] = f2bf(acc[nf][r] * scale);
  }
}

// -- kernel 3: flash attn — 16q/wave, 4-wave kv-split-4 blocks, reg K-dbuf, no LDS loop --
struct Kset { uint4 r[8]; };

__global__ __launch_bounds__(256, 3) void flash_kernel(
    const ushort* __restrict__ qb, const ushort* __restrict__ kb,
    const ushort* __restrict__ vt, float* __restrict__ out) {
  __shared__ float O_l[4][16][68];   // pad 68: breaks the c-stride bank alias
  __shared__ float ml[4][16][2];

  const int tid = threadIdx.x;
  const int lane = tid & 63;
  const int w = tid >> 6;
  const int c = lane & 15, g = lane >> 4;

  const int bid = blockIdx.x;
  const int b = bid & 3;
  const int qt = 255 - (bid >> 2);       // LPT: longest bands first
  const int q0 = qt << 4;
  const int nkt = (qt >> 2) + 1;         // 64-key tiles in this band's causal range

  const char* kbbB = (const char*)(kb + (size_t)b * SEQ * HEAD);
  const char* vtbB = (const char*)(vt + (size_t)b * HEAD * SEQ);

  // Q fragments: query = q0 + c, contiguous-8 k slots (pre-scaled by 0.125*log2e)
  const ushort* qrow = qb + (size_t)(b * SEQ + q0 + c) * HEAD + 8 * g;
  const short8 qa0 = ld16(qrow);
  const short8 qa1 = ld16(qrow + 32);

  f32x4 O[4];
#pragma unroll
  for (int i = 0; i < 4; ++i) O[i] = {0.f, 0.f, 0.f, 0.f};
  float m = -1e30f, l = 0.f;

  // per-wave tile sequence: kt = w, w+4, ...
  const char* kp = kbbB + (size_t)(64 * w + c) * 128 + 16 * g;
  const char* vp = vtbB + (size_t)c * 8192 + 128 * w + 8 * g;

#define LOADK(SET, KPTR)                                      \
  do {                                                        \
    _Pragma("unroll") for (int nf = 0; nf < 4; ++nf) {        \
      (SET).r[2 * nf]     = *(const uint4*)((KPTR) + nf * 2048);      \
      (SET).r[2 * nf + 1] = *(const uint4*)((KPTR) + nf * 2048 + 64); \
    }                                                         \
  } while (0)

  auto compute = [&](const Kset& kk, int kt, const char* vpc) {
    // ---- V loads issued first: consumed after softmax (latency hidden) ----
    uint2 vv[16];
#pragma unroll
    for (int nf = 0; nf < 4; ++nf)
#pragma unroll
      for (int sl = 0; sl < 2; ++sl) {
        vv[nf * 4 + sl * 2]     = *(const uint2*)(vpc + nf * 131072 + 64 * sl);
        vv[nf * 4 + sl * 2 + 1] = *(const uint2*)(vpc + nf * 131072 + 64 * sl + 32);
      }

    // ---- S^T = K Q^T : frag nf reg rr : key = 64kt+16nf+4g+rr, query = q0+c ----
    f32x4 Sf[4];
#pragma unroll
    for (int i = 0; i < 4; ++i) Sf[i] = {0.f, 0.f, 0.f, 0.f};
#pragma unroll
    for (int nf = 0; nf < 4; ++nf) {
      S8u ka0, ka1;
      ka0.u[0] = kk.r[2 * nf].x; ka0.u[1] = kk.r[2 * nf].y;
      ka0.u[2] = kk.r[2 * nf].z; ka0.u[3] = kk.r[2 * nf].w;
      ka1.u[0] = kk.r[2 * nf + 1].x; ka1.u[1] = kk.r[2 * nf + 1].y;
      ka1.u[2] = kk.r[2 * nf + 1].z; ka1.u[3] = kk.r[2 * nf + 1].w;
      Sf[nf] = __builtin_amdgcn_mfma_f32_16x16x32_bf16(ka0.v, qa0, Sf[nf], 0, 0, 0);
      Sf[nf] = __builtin_amdgcn_mfma_f32_16x16x32_bf16(ka1.v, qa1, Sf[nf], 0, 0, 0);
    }

    // ---- causal mask: only the band's last tile crosses the diagonal ----
    if (kt == nkt - 1) {
      int k0 = kt << 6;
#pragma unroll
      for (int nf = 0; nf < 4; ++nf)
#pragma unroll
        for (int rr = 0; rr < 4; ++rr)
          if (k0 + nf * 16 + 4 * g + rr > q0 + c) Sf[nf][rr] = -1e30f;
    }

    // ---- online softmax (exp2 domain; per-tile rescale) ----
    float x0 = fmaxf(fmaxf(Sf[0][0], Sf[0][1]), fmaxf(Sf[0][2], Sf[0][3]));
    float x1 = fmaxf(fmaxf(Sf[1][0], Sf[1][1]), fmaxf(Sf[1][2], Sf[1][3]));
    float x2 = fmaxf(fmaxf(Sf[2][0], Sf[2][1]), fmaxf(Sf[2][2], Sf[2][3]));
    float x3 = fmaxf(fmaxf(Sf[3][0], Sf[3][1]), fmaxf(Sf[3][2], Sf[3][3]));
    float rm = fmaxf(fmaxf(x0, x1), fmaxf(x2, x3));
    rm = fmaxf(rm, __shfl_xor(rm, 16));
    rm = fmaxf(rm, __shfl_xor(rm, 32));
    rm = fmaxf(rm, m);
    float alpha = exp2f(m - rm);
    m = rm;
#pragma unroll
    for (int nf = 0; nf < 4; ++nf)
#pragma unroll
      for (int rr = 0; rr < 4; ++rr)
        Sf[nf][rr] = exp2f(Sf[nf][rr] - rm);
    float s0 = (Sf[0][0] + Sf[0][1]) + (Sf[0][2] + Sf[0][3]);
    float s1 = (Sf[1][0] + Sf[1][1]) + (Sf[1][2] + Sf[1][3]);
    float s2 = (Sf[2][0] + Sf[2][1]) + (Sf[2][2] + Sf[2][3]);
    float s3 = (Sf[3][0] + Sf[3][1]) + (Sf[3][2] + Sf[3][3]);
    float rs = (s0 + s1) + (s2 + s3);
    rs += __shfl_xor(rs, 16);
    rs += __shfl_xor(rs, 32);
    l = l * alpha + rs;
#pragma unroll
    for (int nf = 0; nf < 4; ++nf)
#pragma unroll
      for (int rr = 0; rr < 4; ++rr)
        O[nf][rr] *= alpha;

    // ---- O^T += V^T P : P already in B-fragment layout ----
#pragma unroll
    for (int sl = 0; sl < 2; ++sl) {
      S8u pa;
#pragma unroll
      for (int rr = 0; rr < 4; ++rr) {
        pa.s[rr]     = f2bf(Sf[2 * sl][rr]);
        pa.s[rr + 4] = f2bf(Sf[2 * sl + 1][rr]);
      }
#pragma unroll
      for (int nf = 0; nf < 4; ++nf) {
        S8u vbf;
        uint2 lo = vv[nf * 4 + sl * 2];
        uint2 hi = vv[nf * 4 + sl * 2 + 1];
        vbf.u[0] = lo.x; vbf.u[1] = lo.y; vbf.u[2] = hi.x; vbf.u[3] = hi.y;
        O[nf] = __builtin_amdgcn_mfma_f32_16x16x32_bf16(vbf.v, pa.v, O[nf], 0, 0, 0);
      }
    }
  };

  // ---- software-pipelined kv loop (2-deep, named K sets; V single-buffered) ----
  Kset kA, kB;
  int kt = w;
  if (kt < nkt) {
    LOADK(kA, kp);
    while (true) {
      if (kt + 4 < nkt) LOADK(kB, kp + 32768);
      compute(kA, kt, vp);
      kt += 4; kp += 32768; vp += 512;
      if (kt >= nkt) break;
      if (kt + 4 < nkt) LOADK(kA, kp + 32768);
      compute(kB, kt, vp);
      kt += 4; kp += 32768; vp += 512;
      if (kt >= nkt) break;
    }
  }
#undef LOADK

  // ---- partials -> LDS ----
#pragma unroll
  for (int nf = 0; nf < 4; ++nf)
    *(f32x4*)&O_l[w][c][16 * nf + 4 * g] = O[nf];   // O^T[d][q=c] -> O_l[w][q][d]
  if (g == 0) {
    ml[w][c][0] = m;
    ml[w][c][1] = l;
  }
  __syncthreads();

  // ---- merge 4 kv-split partials: 256 threads = 16 q x 16 d-quads ----
  {
    int q = tid >> 4;
    int dq = tid & 15;
    float mm[4], M = -1e30f;
#pragma unroll
    for (int w2 = 0; w2 < 4; ++w2) { mm[w2] = ml[w2][q][0]; M = fmaxf(M, mm[w2]); }
    float wgt[4], L = 0.f;
#pragma unroll
    for (int w2 = 0; w2 < 4; ++w2) {
      wgt[w2] = exp2f(mm[w2] - M);   // idle waves: exp2(-1e30 - M) -> 0
      L += wgt[w2] * ml[w2][q][1];
    }
    f32x4 acc = {0.f, 0.f, 0.f, 0.f};
#pragma unroll
    for (int w2 = 0; w2 < 4; ++w2) {
      f32x4 t = *(const f32x4*)&O_l[w2][q][4 * dq];
#pragma unroll
      for (int rr = 0; rr < 4; ++rr) acc[rr] += wgt[w2] * t[rr];
    }
    float inv = 1.0f / L;
    f32x4 res;
#pragma unroll
    for (int rr = 0; rr < 4; ++rr) res[rr] = acc[rr] * inv;
    *(f32x4*)&out[(size_t)(b * SEQ + q0 + q) * HEAD + 4 * dq] = res;
  }
}

extern "C" void kernel_launch(void* const* d_in, const int* in_sizes, int n_in,
                              void* d_out, int out_size, void* d_ws, size_t ws_size,
                              hipStream_t stream) {
  const float* qsrc = (const float*)d_in[0];
  const float* ksrc = (const float*)d_in[1];
  const float* vsrc = (const float*)d_in[2];
  const float* wq = (const float*)d_in[3];
  const float* wk = (const float*)d_in[4];
  const float* wv = (const float*)d_in[5];
  float* out = (float*)d_out;

  char* ws = (char*)d_ws;
  ushort* wT = (ushort*)ws;                           // 384 KB
  ushort* qb = (ushort*)(ws + 393216);                // 2 MB
  ushort* kb = (ushort*)(ws + 393216 + 2097152);      // 2 MB
  ushort* vt = (ushort*)(ws + 393216 + 2 * 2097152);  // 2 MB (transposed V)

  prep_w<<<dim3(768), dim3(256), 0, stream>>>(wq, wk, wv, wT);
  proj_kernel<<<dim3(256, 3), dim3(256), 0, stream>>>(qsrc, ksrc, vsrc, wT, qb, kb, vt);
  flash_kernel<<<dim3(1024), dim3(256), 0, stream>>>(qb, kb, vt, out);
}